// Round 5
// baseline (39061.771 us; speedup 1.0000x reference)
//
#include <hip/hip_runtime.h>

typedef unsigned short u16;
typedef __attribute__((ext_vector_type(8))) short s16x8;
typedef __attribute__((ext_vector_type(4))) float f32x4;
typedef __attribute__((ext_vector_type(4))) unsigned int u32x4;
typedef __attribute__((ext_vector_type(4))) unsigned short u16x4;

#define RG 16  // reservoir blocks

__device__ __forceinline__ float b2f(u16 u) {
  return __uint_as_float(((unsigned int)u) << 16);
}
__device__ __forceinline__ u16 f2b(float f) {   // RNE f32 -> bf16
  unsigned int x = __float_as_uint(f);
  x += 0x7fffu + ((x >> 16) & 1u);
  return (u16)(x >> 16);
}

// ---------------- f32 -> bf16 cast, 4 elems/thread ----------------
__global__ void cast_ker(const float* __restrict__ in, u16* __restrict__ out, int n4) {
  int i = blockIdx.x * blockDim.x + threadIdx.x;
  if (i >= n4) return;
  f32x4 v = ((const f32x4*)in)[i];
  u16x4 o;
  o.x = f2b(v.x); o.y = f2b(v.y); o.z = f2b(v.z); o.w = f2b(v.w);
  ((u16x4*)out)[i] = o;
}

// ---------------- GEMM: C[M,N] = act(Abf16[M,K] @ Bbf16[N,K]^T + biasf32) ----------------
template<int ACT, int BIAS, int WF32, int WB16>
__global__ __launch_bounds__(256)
void gemm_bt(const u16* __restrict__ A, const u16* __restrict__ B,
             const float* __restrict__ bias, float* __restrict__ Cf,
             u16* __restrict__ Cb, int M, int N, int K) {
  __shared__ u16 As[128 * 40];
  __shared__ u16 Bs[128 * 40];
  const int tid  = threadIdx.x;
  const int lane = tid & 63;
  const int wave = tid >> 6;
  const int wm = wave >> 1, wn = wave & 1;
  const int bm = blockIdx.x << 7;
  const int bn = blockIdx.y << 7;
  const int sr = tid >> 2;
  const int sc = (tid & 3) << 3;

  f32x4 acc[4][4];
#pragma unroll
  for (int m = 0; m < 4; ++m)
#pragma unroll
    for (int n = 0; n < 4; ++n) acc[m][n] = f32x4{0.f, 0.f, 0.f, 0.f};

  const int row0 = (wm << 6) + (lane & 15);
  const int col0 = (wn << 6) + (lane & 15);
  const int k8   = (lane >> 4) << 3;

  for (int kt = 0; kt < K; kt += 32) {
    u32x4 a0 = *(const u32x4*)(A + (size_t)(bm + sr) * K + kt + sc);
    u32x4 a1 = *(const u32x4*)(A + (size_t)(bm + sr + 64) * K + kt + sc);
    u32x4 b0 = *(const u32x4*)(B + (size_t)(bn + sr) * K + kt + sc);
    u32x4 b1 = *(const u32x4*)(B + (size_t)(bn + sr + 64) * K + kt + sc);
    __syncthreads();
    *(u32x4*)(As + sr * 40 + sc) = a0;
    *(u32x4*)(As + (sr + 64) * 40 + sc) = a1;
    *(u32x4*)(Bs + sr * 40 + sc) = b0;
    *(u32x4*)(Bs + (sr + 64) * 40 + sc) = b1;
    __syncthreads();

    s16x8 af[4], bfr[4];
#pragma unroll
    for (int m = 0; m < 4; ++m)
      af[m] = *(const s16x8*)(As + (row0 + m * 16) * 40 + k8);
#pragma unroll
    for (int n = 0; n < 4; ++n)
      bfr[n] = *(const s16x8*)(Bs + (col0 + n * 16) * 40 + k8);
#pragma unroll
    for (int m = 0; m < 4; ++m)
#pragma unroll
      for (int n = 0; n < 4; ++n)
        acc[m][n] = __builtin_amdgcn_mfma_f32_16x16x32_bf16(af[m], bfr[n], acc[m][n], 0, 0, 0);
  }

  const int crow = (wm << 6) + ((lane >> 4) << 2);
  const int ccol = (wn << 6) + (lane & 15);
#pragma unroll
  for (int m = 0; m < 4; ++m) {
#pragma unroll
    for (int n = 0; n < 4; ++n) {
      const int c = bn + ccol + n * 16;
      const float bv = BIAS ? bias[c] : 0.f;
#pragma unroll
      for (int i = 0; i < 4; ++i) {
        const int r = bm + crow + m * 16 + i;
        float v = acc[m][n][i] + bv;
        if (ACT) v = fmaxf(v, 0.f);
        if (WF32) Cf[(size_t)r * N + c] = v;
        if (WB16) Cb[(size_t)r * N + c] = f2b(v);
      }
    }
  }
}

// ---------------- split-precision GEMM: C[M,N] = Af32[M,K] @ Bf32[N,K]^T ----------------
__global__ __launch_bounds__(256)
void gemm_split(const float* __restrict__ A, const float* __restrict__ B,
                float* __restrict__ C, int M, int N, int K) {
  __shared__ u16 Ah[128 * 40];
  __shared__ u16 Al[128 * 40];
  __shared__ u16 Bh[128 * 40];
  __shared__ u16 Bl[128 * 40];
  const int tid  = threadIdx.x;
  const int lane = tid & 63;
  const int wave = tid >> 6;
  const int wm = wave >> 1, wn = wave & 1;
  const int bm = blockIdx.x << 7;
  const int bn = blockIdx.y << 7;
  const int sr = tid >> 2;
  const int sc = (tid & 3) << 3;

  f32x4 acc[4][4];
#pragma unroll
  for (int m = 0; m < 4; ++m)
#pragma unroll
    for (int n = 0; n < 4; ++n) acc[m][n] = f32x4{0.f, 0.f, 0.f, 0.f};

  const int row0 = (wm << 6) + (lane & 15);
  const int col0 = (wn << 6) + (lane & 15);
  const int k8   = (lane >> 4) << 3;

  for (int kt = 0; kt < K; kt += 32) {
    f32x4 a0 = *(const f32x4*)(A + (size_t)(bm + sr) * K + kt + sc);
    f32x4 a1 = *(const f32x4*)(A + (size_t)(bm + sr) * K + kt + sc + 4);
    f32x4 a2 = *(const f32x4*)(A + (size_t)(bm + sr + 64) * K + kt + sc);
    f32x4 a3 = *(const f32x4*)(A + (size_t)(bm + sr + 64) * K + kt + sc + 4);
    f32x4 b0 = *(const f32x4*)(B + (size_t)(bn + sr) * K + kt + sc);
    f32x4 b1 = *(const f32x4*)(B + (size_t)(bn + sr) * K + kt + sc + 4);
    f32x4 b2 = *(const f32x4*)(B + (size_t)(bn + sr + 64) * K + kt + sc);
    f32x4 b3 = *(const f32x4*)(B + (size_t)(bn + sr + 64) * K + kt + sc + 4);
    __syncthreads();
#pragma unroll
    for (int j = 0; j < 4; ++j) {
      float av, rs; u16 h;
      av = a0[j]; h = f2b(av); rs = av - b2f(h);
      Ah[sr * 40 + sc + j] = h;            Al[sr * 40 + sc + j] = f2b(rs);
      av = a1[j]; h = f2b(av); rs = av - b2f(h);
      Ah[sr * 40 + sc + 4 + j] = h;        Al[sr * 40 + sc + 4 + j] = f2b(rs);
      av = a2[j]; h = f2b(av); rs = av - b2f(h);
      Ah[(sr + 64) * 40 + sc + j] = h;     Al[(sr + 64) * 40 + sc + j] = f2b(rs);
      av = a3[j]; h = f2b(av); rs = av - b2f(h);
      Ah[(sr + 64) * 40 + sc + 4 + j] = h; Al[(sr + 64) * 40 + sc + 4 + j] = f2b(rs);
      av = b0[j]; h = f2b(av); rs = av - b2f(h);
      Bh[sr * 40 + sc + j] = h;            Bl[sr * 40 + sc + j] = f2b(rs);
      av = b1[j]; h = f2b(av); rs = av - b2f(h);
      Bh[sr * 40 + sc + 4 + j] = h;        Bl[sr * 40 + sc + 4 + j] = f2b(rs);
      av = b2[j]; h = f2b(av); rs = av - b2f(h);
      Bh[(sr + 64) * 40 + sc + j] = h;     Bl[(sr + 64) * 40 + sc + j] = f2b(rs);
      av = b3[j]; h = f2b(av); rs = av - b2f(h);
      Bh[(sr + 64) * 40 + sc + 4 + j] = h; Bl[(sr + 64) * 40 + sc + 4 + j] = f2b(rs);
    }
    __syncthreads();

    s16x8 afh[4], afl[4], bfh[4], bfl[4];
#pragma unroll
    for (int m = 0; m < 4; ++m) {
      afh[m] = *(const s16x8*)(Ah + (row0 + m * 16) * 40 + k8);
      afl[m] = *(const s16x8*)(Al + (row0 + m * 16) * 40 + k8);
    }
#pragma unroll
    for (int n = 0; n < 4; ++n) {
      bfh[n] = *(const s16x8*)(Bh + (col0 + n * 16) * 40 + k8);
      bfl[n] = *(const s16x8*)(Bl + (col0 + n * 16) * 40 + k8);
    }
#pragma unroll
    for (int m = 0; m < 4; ++m)
#pragma unroll
      for (int n = 0; n < 4; ++n) {
        acc[m][n] = __builtin_amdgcn_mfma_f32_16x16x32_bf16(afh[m], bfh[n], acc[m][n], 0, 0, 0);
        acc[m][n] = __builtin_amdgcn_mfma_f32_16x16x32_bf16(afh[m], bfl[n], acc[m][n], 0, 0, 0);
        acc[m][n] = __builtin_amdgcn_mfma_f32_16x16x32_bf16(afl[m], bfh[n], acc[m][n], 0, 0, 0);
      }
  }

  const int crow = (wm << 6) + ((lane >> 4) << 2);
  const int ccol = (wn << 6) + (lane & 15);
#pragma unroll
  for (int m = 0; m < 4; ++m)
#pragma unroll
    for (int n = 0; n < 4; ++n) {
      const int c = bn + ccol + n * 16;
#pragma unroll
      for (int i = 0; i < 4; ++i)
        C[(size_t)(bm + crow + m * 16 + i) * N + c] = acc[m][n][i];
    }
}

// ---------------- z = mu + eps * exp(0.5*log_var), f32, 4 elems/thread ----------------
__global__ void z_ker(const float* __restrict__ mu, const float* __restrict__ lv,
                      const float* __restrict__ eps, float* __restrict__ z,
                      u16* __restrict__ zb, int n4) {
  int i = blockIdx.x * blockDim.x + threadIdx.x;
  if (i >= n4) return;
  f32x4 m4 = ((const f32x4*)mu)[i];
  f32x4 l4 = ((const f32x4*)lv)[i];
  f32x4 e4 = ((const f32x4*)eps)[i];
  f32x4 o;
  o.x = m4.x + e4.x * __expf(0.5f * l4.x);
  o.y = m4.y + e4.y * __expf(0.5f * l4.y);
  o.z = m4.z + e4.z * __expf(0.5f * l4.z);
  o.w = m4.w + e4.w * __expf(0.5f * l4.w);
  ((f32x4*)z)[i] = o;
  u16x4 ob; ob.x = f2b(o.x); ob.y = f2b(o.y); ob.z = f2b(o.z); ob.w = f2b(o.w);
  ((u16x4*)zb)[i] = ob;
}

// ---------------- reservoir scan: state = tanh(Wrec @ state + u[t]) ----------------
// 16 blocks x 512 thr (8 waves). Wave q owns 8 COMPLETE rows [g*64+q*8, +8).
// Lane L holds w[r][j] = Wrec[row_r][j*64+L] (128 f32, stays in VGPRs) and the full
// state in regs (s[j] = state[j*64+L], 16 f32). Per step: overlapped 16-wide poll of
// pub[t-1] (value-as-flag, s+2 in (1,3), 0 = not ready), 128 fmas, in-wave
// fold+butterfly shuffle reduce (no LDS, no __syncthreads), lanes 0..7 publish.
__global__ __launch_bounds__(512, 1)
void reservoir_ker(const float* __restrict__ Wrec, const float* __restrict__ u,
                   float* __restrict__ pub) {
  const int tid  = threadIdx.x;
  const int lane = tid & 63;
  const int q    = tid >> 6;
  const int g    = blockIdx.x;
  const int rbase = (g << 6) + (q << 3);
  // fold-order row map for lanes 0..7: r = 4*b0 + 2*b1 + b2
  const int rmap = ((lane & 1) << 2) + (lane & 2) + ((lane >> 2) & 1);

  float w[8][16];
#pragma unroll
  for (int r = 0; r < 8; ++r) {
    const float* wp = Wrec + (size_t)(rbase + r) * 1024 + lane;
#pragma unroll
    for (int j = 0; j < 16; ++j) w[r][j] = wp[j << 6];
  }

  float uval = (lane < 8) ? u[rbase + rmap] : 0.f;   // u[0][row]

  float s[16];
  for (int t = 0; t < 8192; ++t) {
    // 1. state s_{t-1}: overlapped poll of 16 slots (col = j*64 + lane)
    if (t == 0) {
#pragma unroll
      for (int j = 0; j < 16; ++j) s[j] = 0.f;
    } else {
      const float* p = pub + (((size_t)(t - 1)) << 10) + lane;
#pragma unroll
      for (int j = 0; j < 16; ++j)
        s[j] = __hip_atomic_load(p + (j << 6), __ATOMIC_RELAXED, __HIP_MEMORY_SCOPE_AGENT);
      bool any = true;
      while (any) {
        any = false;
#pragma unroll
        for (int j = 0; j < 16; ++j)
          if (s[j] == 0.f) {
            s[j] = __hip_atomic_load(p + (j << 6), __ATOMIC_RELAXED, __HIP_MEMORY_SCOPE_AGENT);
            if (s[j] == 0.f) any = true;
          }
      }
#pragma unroll
      for (int j = 0; j < 16; ++j) s[j] -= 2.0f;
    }

    // 2. per-lane partials for this wave's 8 rows (128 fma)
    float v[8];
#pragma unroll
    for (int r = 0; r < 8; ++r) {
      float a0 = 0.f, a1 = 0.f, a2 = 0.f, a3 = 0.f;
#pragma unroll
      for (int j = 0; j < 4; ++j) {
        a0 = fmaf(w[r][4 * j + 0], s[4 * j + 0], a0);
        a1 = fmaf(w[r][4 * j + 1], s[4 * j + 1], a1);
        a2 = fmaf(w[r][4 * j + 2], s[4 * j + 2], a2);
        a3 = fmaf(w[r][4 * j + 3], s[4 * j + 3], a3);
      }
      v[r] = (a0 + a1) + (a2 + a3);
    }

    // 3. in-wave reduce: fold rows into lanes (bits 0..2), butterfly bits 3..5
#pragma unroll
    for (int k = 0; k < 3; ++k) {
      const int nr = 8 >> (k + 1);
      const int bit = (lane >> k) & 1;
#pragma unroll
      for (int i = 0; i < nr; ++i) {
        float a = v[i], b = v[i + nr];
        float sendv = bit ? a : b;
        float recvv = __shfl_xor(sendv, 1 << k, 64);
        v[i] = (bit ? b : a) + recvv;
      }
    }
    v[0] += __shfl_xor(v[0], 8, 64);
    v[0] += __shfl_xor(v[0], 16, 64);
    v[0] += __shfl_xor(v[0], 32, 64);

    // 4. lanes 0..7: tanh + publish row rbase+rmap; prefetch next u
    if (lane < 8) {
      float red = v[0] + uval;
      float e = __expf(2.0f * red);          // fast tanh: 1 - 2/(e^{2x}+1)
      float sv = 1.0f - 2.0f / (e + 1.0f);
      __hip_atomic_store(pub + (((size_t)t) << 10) + rbase + rmap, sv + 2.0f,
                         __ATOMIC_RELAXED, __HIP_MEMORY_SCOPE_AGENT);
      if (t + 1 < 8192)
        uval = u[(((size_t)(t + 1)) << 10) + rbase + rmap];
    }
  }
}

// ---------------- prediction = (pub - 2) @ W_out^T  (C=10 skinny) ----------------
__global__ __launch_bounds__(256)
void pred_ker(const float* __restrict__ hist2, const float* __restrict__ wout,
              float* __restrict__ out) {
  __shared__ float wl[10 * 1024];
  const int tid = threadIdx.x;
  for (int i = tid; i < 10240; i += 256) wl[i] = wout[i];
  __syncthreads();
  const int t = blockIdx.x * 256 + tid;
  const float* h = hist2 + (size_t)t * 1024;
  float acc[10];
#pragma unroll
  for (int c = 0; c < 10; ++c) acc[c] = 0.f;
  for (int j = 0; j < 1024; j += 4) {
    f32x4 v4 = *(const f32x4*)(h + j);
#pragma unroll
    for (int k = 0; k < 4; ++k) {
      float hv = v4[k] - 2.0f;
#pragma unroll
      for (int c = 0; c < 10; ++c) acc[c] = fmaf(hv, wl[c * 1024 + j + k], acc[c]);
    }
  }
#pragma unroll
  for (int c = 0; c < 10; ++c) out[(size_t)t * 10 + c] = acc[c];
}

extern "C" void kernel_launch(void* const* d_in, const int* in_sizes, int n_in,
                              void* d_out, int out_size, void* d_ws, size_t ws_size,
                              hipStream_t stream) {
  const float* data   = (const float*)d_in[0];
  // d_in[1] = label (int, unused)
  const float* eps    = (const float*)d_in[2];
  const float* W_enc1 = (const float*)d_in[3];
  const float* b_enc1 = (const float*)d_in[4];
  const float* W_enc2 = (const float*)d_in[5];
  const float* b_enc2 = (const float*)d_in[6];
  const float* W_mu   = (const float*)d_in[7];
  const float* b_mu   = (const float*)d_in[8];
  const float* W_lv   = (const float*)d_in[9];
  const float* b_lv   = (const float*)d_in[10];
  const float* W_dec1 = (const float*)d_in[11];
  const float* b_dec1 = (const float*)d_in[12];
  const float* W_dec2 = (const float*)d_in[13];
  const float* b_dec2 = (const float*)d_in[14];
  const float* Win    = (const float*)d_in[15];
  const float* Wrec   = (const float*)d_in[16];
  const float* W_out  = (const float*)d_in[17];

  float* out      = (float*)d_out;
  float* out_enc  = out;                       // [8192,512]
  float* out_mu   = out + (size_t)4194304;     // [8192,512]
  float* out_lv   = out + (size_t)8388608;     // [8192,512]
  float* out_z    = out + (size_t)12582912;    // [8192,512]
  float* out_dec  = out + (size_t)16777216;    // [8192,1024]
  float* out_pred = out + (size_t)25165824;    // [8192,10]

  // ws layout (aliased; peak 64 MB):
  //  phase 1: data_b @0 (16M) | wts @16M (2.1M) | ws_h @20M (8M) | encb @28M (8M) | zb @36M (8M)
  //  phase 2: ws_u f32 @0 (32M) | pub f32 @32M (32M, memset AFTER phase-1 kernels)
  char* ws = (char*)d_ws;
  u16*   data_b = (u16*)(ws);
  u16*   wts    = (u16*)(ws + 16777216);
  u16*   w1b    = wts;                 // 524288
  u16*   w2b    = wts + 524288;        // 262144
  u16*   wmub   = wts + 786432;        // 262144
  u16*   wlvb   = wts + 1048576;       // 262144
  u16*   wd1b   = wts + 1310720;       // 262144
  u16*   wd2b   = wts + 1572864;       // 524288
  u16*   ws_h   = (u16*)(ws + 20971520);       // 8 MB
  u16*   encb   = (u16*)(ws + 29360128);       // 8 MB
  u16*   zb     = (u16*)(ws + 37748736);       // 8 MB
  float* ws_u   = (float*)(ws);                // 32 MB (after phase 1)
  float* pub    = (float*)(ws + 33554432);     // 32 MB (state history + 2.0)

  dim3 blk(256);
  // casts (f32 -> bf16)
  cast_ker<<<8192, blk, 0, stream>>>(data,   data_b, 2097152);
  cast_ker<<<512,  blk, 0, stream>>>(W_enc1, w1b,    131072);
  cast_ker<<<256,  blk, 0, stream>>>(W_enc2, w2b,    65536);
  cast_ker<<<256,  blk, 0, stream>>>(W_mu,   wmub,   65536);
  cast_ker<<<256,  blk, 0, stream>>>(W_lv,   wlvb,   65536);
  cast_ker<<<256,  blk, 0, stream>>>(W_dec1, wd1b,   65536);
  cast_ker<<<512,  blk, 0, stream>>>(W_dec2, wd2b,   131072);

  // VAE
  gemm_bt<1,1,0,1><<<dim3(64,4), blk, 0, stream>>>(data_b, w1b,  b_enc1, nullptr, ws_h,   8192, 512, 1024);
  gemm_bt<1,1,1,1><<<dim3(64,4), blk, 0, stream>>>(ws_h,   w2b,  b_enc2, out_enc, encb,   8192, 512, 512);
  gemm_bt<0,1,1,0><<<dim3(64,4), blk, 0, stream>>>(encb,   wmub, b_mu,   out_mu,  nullptr,8192, 512, 512);
  gemm_bt<0,1,1,0><<<dim3(64,4), blk, 0, stream>>>(encb,   wlvb, b_lv,   out_lv,  nullptr,8192, 512, 512);
  z_ker<<<4096, blk, 0, stream>>>(out_mu, out_lv, eps, out_z, zb, 1048576);
  gemm_bt<1,1,0,1><<<dim3(64,4), blk, 0, stream>>>(zb,     wd1b, b_dec1, nullptr, ws_h,   8192, 512, 512);
  gemm_bt<0,1,1,0><<<dim3(64,8), blk, 0, stream>>>(ws_h,   wd2b, b_dec2, out_dec, nullptr,8192, 1024, 512);

  // u = z @ Win^T in ~f32 precision (feeds 8192-step recurrence)
  gemm_split<<<dim3(64,8), blk, 0, stream>>>(out_z, Win, ws_u, 8192, 1024, 512);

  // zero pub AFTER phase-1 kernels that alias it (encb/zb) are done, before reservoir.
  // Required every call: pub persists across graph replays and 0 == "not ready".
  (void)hipMemsetAsync(pub, 0, (size_t)33554432, stream);

  // reservoir + readout
  reservoir_ker<<<RG, dim3(512), 0, stream>>>(Wrec, ws_u, pub);
  pred_ker<<<32, blk, 0, stream>>>(pub, W_out, out_pred);
}

// Round 6
// 17066.911 us; speedup vs baseline: 2.2887x; 2.2887x over previous
//
#include <hip/hip_runtime.h>

typedef unsigned short u16;
typedef __attribute__((ext_vector_type(8))) short s16x8;
typedef __attribute__((ext_vector_type(4))) float f32x4;
typedef __attribute__((ext_vector_type(4))) unsigned int u32x4;
typedef __attribute__((ext_vector_type(4))) unsigned short u16x4;

#define RG 16  // reservoir blocks

__device__ __forceinline__ float b2f(u16 u) {
  return __uint_as_float(((unsigned int)u) << 16);
}
__device__ __forceinline__ u16 f2b(float f) {   // RNE f32 -> bf16
  unsigned int x = __float_as_uint(f);
  x += 0x7fffu + ((x >> 16) & 1u);
  return (u16)(x >> 16);
}

// ---------------- f32 -> bf16 cast, 4 elems/thread ----------------
__global__ void cast_ker(const float* __restrict__ in, u16* __restrict__ out, int n4) {
  int i = blockIdx.x * blockDim.x + threadIdx.x;
  if (i >= n4) return;
  f32x4 v = ((const f32x4*)in)[i];
  u16x4 o;
  o.x = f2b(v.x); o.y = f2b(v.y); o.z = f2b(v.z); o.w = f2b(v.w);
  ((u16x4*)out)[i] = o;
}

// ---------------- GEMM: C[M,N] = act(Abf16[M,K] @ Bbf16[N,K]^T + biasf32) ----------------
template<int ACT, int BIAS, int WF32, int WB16>
__global__ __launch_bounds__(256)
void gemm_bt(const u16* __restrict__ A, const u16* __restrict__ B,
             const float* __restrict__ bias, float* __restrict__ Cf,
             u16* __restrict__ Cb, int M, int N, int K) {
  __shared__ u16 As[128 * 40];
  __shared__ u16 Bs[128 * 40];
  const int tid  = threadIdx.x;
  const int lane = tid & 63;
  const int wave = tid >> 6;
  const int wm = wave >> 1, wn = wave & 1;
  const int bm = blockIdx.x << 7;
  const int bn = blockIdx.y << 7;
  const int sr = tid >> 2;
  const int sc = (tid & 3) << 3;

  f32x4 acc[4][4];
#pragma unroll
  for (int m = 0; m < 4; ++m)
#pragma unroll
    for (int n = 0; n < 4; ++n) acc[m][n] = f32x4{0.f, 0.f, 0.f, 0.f};

  const int row0 = (wm << 6) + (lane & 15);
  const int col0 = (wn << 6) + (lane & 15);
  const int k8   = (lane >> 4) << 3;

  for (int kt = 0; kt < K; kt += 32) {
    u32x4 a0 = *(const u32x4*)(A + (size_t)(bm + sr) * K + kt + sc);
    u32x4 a1 = *(const u32x4*)(A + (size_t)(bm + sr + 64) * K + kt + sc);
    u32x4 b0 = *(const u32x4*)(B + (size_t)(bn + sr) * K + kt + sc);
    u32x4 b1 = *(const u32x4*)(B + (size_t)(bn + sr + 64) * K + kt + sc);
    __syncthreads();
    *(u32x4*)(As + sr * 40 + sc) = a0;
    *(u32x4*)(As + (sr + 64) * 40 + sc) = a1;
    *(u32x4*)(Bs + sr * 40 + sc) = b0;
    *(u32x4*)(Bs + (sr + 64) * 40 + sc) = b1;
    __syncthreads();

    s16x8 af[4], bfr[4];
#pragma unroll
    for (int m = 0; m < 4; ++m)
      af[m] = *(const s16x8*)(As + (row0 + m * 16) * 40 + k8);
#pragma unroll
    for (int n = 0; n < 4; ++n)
      bfr[n] = *(const s16x8*)(Bs + (col0 + n * 16) * 40 + k8);
#pragma unroll
    for (int m = 0; m < 4; ++m)
#pragma unroll
      for (int n = 0; n < 4; ++n)
        acc[m][n] = __builtin_amdgcn_mfma_f32_16x16x32_bf16(af[m], bfr[n], acc[m][n], 0, 0, 0);
  }

  const int crow = (wm << 6) + ((lane >> 4) << 2);
  const int ccol = (wn << 6) + (lane & 15);
#pragma unroll
  for (int m = 0; m < 4; ++m) {
#pragma unroll
    for (int n = 0; n < 4; ++n) {
      const int c = bn + ccol + n * 16;
      const float bv = BIAS ? bias[c] : 0.f;
#pragma unroll
      for (int i = 0; i < 4; ++i) {
        const int r = bm + crow + m * 16 + i;
        float v = acc[m][n][i] + bv;
        if (ACT) v = fmaxf(v, 0.f);
        if (WF32) Cf[(size_t)r * N + c] = v;
        if (WB16) Cb[(size_t)r * N + c] = f2b(v);
      }
    }
  }
}

// ---------------- split-precision GEMM: C[M,N] = Af32[M,K] @ Bf32[N,K]^T ----------------
__global__ __launch_bounds__(256)
void gemm_split(const float* __restrict__ A, const float* __restrict__ B,
                float* __restrict__ C, int M, int N, int K) {
  __shared__ u16 Ah[128 * 40];
  __shared__ u16 Al[128 * 40];
  __shared__ u16 Bh[128 * 40];
  __shared__ u16 Bl[128 * 40];
  const int tid  = threadIdx.x;
  const int lane = tid & 63;
  const int wave = tid >> 6;
  const int wm = wave >> 1, wn = wave & 1;
  const int bm = blockIdx.x << 7;
  const int bn = blockIdx.y << 7;
  const int sr = tid >> 2;
  const int sc = (tid & 3) << 3;

  f32x4 acc[4][4];
#pragma unroll
  for (int m = 0; m < 4; ++m)
#pragma unroll
    for (int n = 0; n < 4; ++n) acc[m][n] = f32x4{0.f, 0.f, 0.f, 0.f};

  const int row0 = (wm << 6) + (lane & 15);
  const int col0 = (wn << 6) + (lane & 15);
  const int k8   = (lane >> 4) << 3;

  for (int kt = 0; kt < K; kt += 32) {
    f32x4 a0 = *(const f32x4*)(A + (size_t)(bm + sr) * K + kt + sc);
    f32x4 a1 = *(const f32x4*)(A + (size_t)(bm + sr) * K + kt + sc + 4);
    f32x4 a2 = *(const f32x4*)(A + (size_t)(bm + sr + 64) * K + kt + sc);
    f32x4 a3 = *(const f32x4*)(A + (size_t)(bm + sr + 64) * K + kt + sc + 4);
    f32x4 b0 = *(const f32x4*)(B + (size_t)(bn + sr) * K + kt + sc);
    f32x4 b1 = *(const f32x4*)(B + (size_t)(bn + sr) * K + kt + sc + 4);
    f32x4 b2 = *(const f32x4*)(B + (size_t)(bn + sr + 64) * K + kt + sc);
    f32x4 b3 = *(const f32x4*)(B + (size_t)(bn + sr + 64) * K + kt + sc + 4);
    __syncthreads();
#pragma unroll
    for (int j = 0; j < 4; ++j) {
      float av, rs; u16 h;
      av = a0[j]; h = f2b(av); rs = av - b2f(h);
      Ah[sr * 40 + sc + j] = h;            Al[sr * 40 + sc + j] = f2b(rs);
      av = a1[j]; h = f2b(av); rs = av - b2f(h);
      Ah[sr * 40 + sc + 4 + j] = h;        Al[sr * 40 + sc + 4 + j] = f2b(rs);
      av = a2[j]; h = f2b(av); rs = av - b2f(h);
      Ah[(sr + 64) * 40 + sc + j] = h;     Al[(sr + 64) * 40 + sc + j] = f2b(rs);
      av = a3[j]; h = f2b(av); rs = av - b2f(h);
      Ah[(sr + 64) * 40 + sc + 4 + j] = h; Al[(sr + 64) * 40 + sc + 4 + j] = f2b(rs);
      av = b0[j]; h = f2b(av); rs = av - b2f(h);
      Bh[sr * 40 + sc + j] = h;            Bl[sr * 40 + sc + j] = f2b(rs);
      av = b1[j]; h = f2b(av); rs = av - b2f(h);
      Bh[sr * 40 + sc + 4 + j] = h;        Bl[sr * 40 + sc + 4 + j] = f2b(rs);
      av = b2[j]; h = f2b(av); rs = av - b2f(h);
      Bh[(sr + 64) * 40 + sc + j] = h;     Bl[(sr + 64) * 40 + sc + j] = f2b(rs);
      av = b3[j]; h = f2b(av); rs = av - b2f(h);
      Bh[(sr + 64) * 40 + sc + 4 + j] = h; Bl[(sr + 64) * 40 + sc + 4 + j] = f2b(rs);
    }
    __syncthreads();

    s16x8 afh[4], afl[4], bfh[4], bfl[4];
#pragma unroll
    for (int m = 0; m < 4; ++m) {
      afh[m] = *(const s16x8*)(Ah + (row0 + m * 16) * 40 + k8);
      afl[m] = *(const s16x8*)(Al + (row0 + m * 16) * 40 + k8);
    }
#pragma unroll
    for (int n = 0; n < 4; ++n) {
      bfh[n] = *(const s16x8*)(Bh + (col0 + n * 16) * 40 + k8);
      bfl[n] = *(const s16x8*)(Bl + (col0 + n * 16) * 40 + k8);
    }
#pragma unroll
    for (int m = 0; m < 4; ++m)
#pragma unroll
      for (int n = 0; n < 4; ++n) {
        acc[m][n] = __builtin_amdgcn_mfma_f32_16x16x32_bf16(afh[m], bfh[n], acc[m][n], 0, 0, 0);
        acc[m][n] = __builtin_amdgcn_mfma_f32_16x16x32_bf16(afh[m], bfl[n], acc[m][n], 0, 0, 0);
        acc[m][n] = __builtin_amdgcn_mfma_f32_16x16x32_bf16(afl[m], bfh[n], acc[m][n], 0, 0, 0);
      }
  }

  const int crow = (wm << 6) + ((lane >> 4) << 2);
  const int ccol = (wn << 6) + (lane & 15);
#pragma unroll
  for (int m = 0; m < 4; ++m)
#pragma unroll
    for (int n = 0; n < 4; ++n) {
      const int c = bn + ccol + n * 16;
#pragma unroll
      for (int i = 0; i < 4; ++i)
        C[(size_t)(bm + crow + m * 16 + i) * N + c] = acc[m][n][i];
    }
}

// ---------------- z = mu + eps * exp(0.5*log_var), f32, 4 elems/thread ----------------
__global__ void z_ker(const float* __restrict__ mu, const float* __restrict__ lv,
                      const float* __restrict__ eps, float* __restrict__ z,
                      u16* __restrict__ zb, int n4) {
  int i = blockIdx.x * blockDim.x + threadIdx.x;
  if (i >= n4) return;
  f32x4 m4 = ((const f32x4*)mu)[i];
  f32x4 l4 = ((const f32x4*)lv)[i];
  f32x4 e4 = ((const f32x4*)eps)[i];
  f32x4 o;
  o.x = m4.x + e4.x * __expf(0.5f * l4.x);
  o.y = m4.y + e4.y * __expf(0.5f * l4.y);
  o.z = m4.z + e4.z * __expf(0.5f * l4.z);
  o.w = m4.w + e4.w * __expf(0.5f * l4.w);
  ((f32x4*)z)[i] = o;
  u16x4 ob; ob.x = f2b(o.x); ob.y = f2b(o.y); ob.z = f2b(o.z); ob.w = f2b(o.w);
  ((u16x4*)zb)[i] = ob;
}

// ---------------- reservoir scan: state = tanh(Wrec @ state + u[t]) ----------------
// 16 blocks x 256 thr (4 waves). Block g owns rows [g*64,+64). Wave q polls ONLY its
// private col slice [q*256,+256) (4 slots/lane, issued concurrently, re-poll zeros).
// pub holds RAW values s+2 in (1,3); 0 == not ready (value-as-flag, write-once/step).
// Dot uses raw values; the -2 bias folds into precomputed 2*rowsum(w) per lane.
// Tail: ONE barrier, then each wave reduces+publishes its own 16 rows (prow).
// part[] double-buffered on t&1 -> no second barrier (intra-block skew <= 1 step).
__global__ __launch_bounds__(256, 1)
void reservoir_ker(const float* __restrict__ Wrec, const float* __restrict__ u,
                   float* __restrict__ pub) {
  __shared__ float st[4][256];        // wave-private raw state slice
  __shared__ float part[2][4][64];    // [t&1][wave][row]
  const int tid  = threadIdx.x;
  const int lane = tid & 63;
  const int q    = tid >> 6;
  const int g    = blockIdx.x;
  const int row  = (g << 6) + lane;          // dot row for this lane
  const int prow = (q << 4) + (lane & 15);   // publish row (within block) for tail

  float w[256]; float wsum = 0.f;
  {
    const float* wp = Wrec + (size_t)row * 1024 + (q << 8);
#pragma unroll
    for (int j = 0; j < 64; ++j) {
      f32x4 v = *(const f32x4*)(wp + j * 4);
      w[4 * j + 0] = v.x; w[4 * j + 1] = v.y; w[4 * j + 2] = v.z; w[4 * j + 3] = v.w;
      wsum += (v.x + v.y) + (v.z + v.w);
    }
  }
  const float wsum2 = 2.0f * wsum;

  float uval = u[(g << 6) + prow];   // u[0][publish row]

  for (int t = 0; t < 8192; ++t) {
    // 1. obtain raw state (s_{t-1}+2) for this wave's 256 cols; t==0 -> s=0 -> raw=2
    if (t == 0) {
      st[q][lane] = 2.0f; st[q][lane + 64] = 2.0f;
      st[q][lane + 128] = 2.0f; st[q][lane + 192] = 2.0f;
    } else {
      const float* p = pub + (((size_t)(t - 1)) << 10) + (q << 8) + lane;
      float v0 = __hip_atomic_load(p,       __ATOMIC_RELAXED, __HIP_MEMORY_SCOPE_AGENT);
      float v1 = __hip_atomic_load(p + 64,  __ATOMIC_RELAXED, __HIP_MEMORY_SCOPE_AGENT);
      float v2 = __hip_atomic_load(p + 128, __ATOMIC_RELAXED, __HIP_MEMORY_SCOPE_AGENT);
      float v3 = __hip_atomic_load(p + 192, __ATOMIC_RELAXED, __HIP_MEMORY_SCOPE_AGENT);
      while (v0 == 0.f || v1 == 0.f || v2 == 0.f || v3 == 0.f) {
        if (v0 == 0.f) v0 = __hip_atomic_load(p,       __ATOMIC_RELAXED, __HIP_MEMORY_SCOPE_AGENT);
        if (v1 == 0.f) v1 = __hip_atomic_load(p + 64,  __ATOMIC_RELAXED, __HIP_MEMORY_SCOPE_AGENT);
        if (v2 == 0.f) v2 = __hip_atomic_load(p + 128, __ATOMIC_RELAXED, __HIP_MEMORY_SCOPE_AGENT);
        if (v3 == 0.f) v3 = __hip_atomic_load(p + 192, __ATOMIC_RELAXED, __HIP_MEMORY_SCOPE_AGENT);
      }
      st[q][lane]       = v0;
      st[q][lane + 64]  = v1;
      st[q][lane + 128] = v2;
      st[q][lane + 192] = v3;
    }
    // intra-wave LDS write->read ordering (no cross-wave dependency on st)
    asm volatile("s_waitcnt lgkmcnt(0)" ::: "memory");

    // 2. partial dot over raw values (LDS reads broadcast); -2 bias folded via wsum2
    float ac0 = 0.f, ac1 = 0.f, ac2 = 0.f, ac3 = 0.f;
    const float* sp = &st[q][0];
#pragma unroll
    for (int j = 0; j < 64; ++j) {
      f32x4 s4 = *(const f32x4*)(sp + (j << 2));
      ac0 = fmaf(w[4 * j + 0], s4.x, ac0);
      ac1 = fmaf(w[4 * j + 1], s4.y, ac1);
      ac2 = fmaf(w[4 * j + 2], s4.z, ac2);
      ac3 = fmaf(w[4 * j + 3], s4.w, ac3);
    }
    part[t & 1][q][lane] = ((ac0 + ac1) + (ac2 + ac3)) - wsum2;
    __syncthreads();   // single barrier: all partials of this parity visible

    // 3. every wave finalizes its own 16 rows (4-way redundant across lane groups)
    float red = ((part[t & 1][0][prow] + part[t & 1][1][prow]) +
                 (part[t & 1][2][prow] + part[t & 1][3][prow])) + uval;
    float e  = __expf(2.0f * red);           // fast tanh: 1 - 2/(e^{2x}+1)
    float sv = 1.0f - 2.0f / (e + 1.0f);
    if (lane < 16)
      __hip_atomic_store(pub + (((size_t)t) << 10) + (g << 6) + prow, sv + 2.0f,
                         __ATOMIC_RELAXED, __HIP_MEMORY_SCOPE_AGENT);
    if (t + 1 < 8192)
      uval = u[(((size_t)(t + 1)) << 10) + (g << 6) + prow];
  }
}

// ---------------- prediction = (pub - 2) @ W_out^T  (C=10 skinny) ----------------
__global__ __launch_bounds__(256)
void pred_ker(const float* __restrict__ hist2, const float* __restrict__ wout,
              float* __restrict__ out) {
  __shared__ float wl[10 * 1024];
  const int tid = threadIdx.x;
  for (int i = tid; i < 10240; i += 256) wl[i] = wout[i];
  __syncthreads();
  const int t = blockIdx.x * 256 + tid;
  const float* h = hist2 + (size_t)t * 1024;
  float acc[10];
#pragma unroll
  for (int c = 0; c < 10; ++c) acc[c] = 0.f;
  for (int j = 0; j < 1024; j += 4) {
    f32x4 v4 = *(const f32x4*)(h + j);
#pragma unroll
    for (int k = 0; k < 4; ++k) {
      float hv = v4[k] - 2.0f;
#pragma unroll
      for (int c = 0; c < 10; ++c) acc[c] = fmaf(hv, wl[c * 1024 + j + k], acc[c]);
    }
  }
#pragma unroll
  for (int c = 0; c < 10; ++c) out[(size_t)t * 10 + c] = acc[c];
}

extern "C" void kernel_launch(void* const* d_in, const int* in_sizes, int n_in,
                              void* d_out, int out_size, void* d_ws, size_t ws_size,
                              hipStream_t stream) {
  const float* data   = (const float*)d_in[0];
  // d_in[1] = label (int, unused)
  const float* eps    = (const float*)d_in[2];
  const float* W_enc1 = (const float*)d_in[3];
  const float* b_enc1 = (const float*)d_in[4];
  const float* W_enc2 = (const float*)d_in[5];
  const float* b_enc2 = (const float*)d_in[6];
  const float* W_mu   = (const float*)d_in[7];
  const float* b_mu   = (const float*)d_in[8];
  const float* W_lv   = (const float*)d_in[9];
  const float* b_lv   = (const float*)d_in[10];
  const float* W_dec1 = (const float*)d_in[11];
  const float* b_dec1 = (const float*)d_in[12];
  const float* W_dec2 = (const float*)d_in[13];
  const float* b_dec2 = (const float*)d_in[14];
  const float* Win    = (const float*)d_in[15];
  const float* Wrec   = (const float*)d_in[16];
  const float* W_out  = (const float*)d_in[17];

  float* out      = (float*)d_out;
  float* out_enc  = out;                       // [8192,512]
  float* out_mu   = out + (size_t)4194304;     // [8192,512]
  float* out_lv   = out + (size_t)8388608;     // [8192,512]
  float* out_z    = out + (size_t)12582912;    // [8192,512]
  float* out_dec  = out + (size_t)16777216;    // [8192,1024]
  float* out_pred = out + (size_t)25165824;    // [8192,10]

  // ws layout (aliased; peak 64 MB):
  //  phase 1: data_b @0 (16M) | wts @16M (2.1M) | ws_h @20M (8M) | encb @28M (8M) | zb @36M (8M)
  //  phase 2: ws_u f32 @0 (32M) | pub f32 @32M (32M, memset AFTER phase-1 kernels)
  char* ws = (char*)d_ws;
  u16*   data_b = (u16*)(ws);
  u16*   wts    = (u16*)(ws + 16777216);
  u16*   w1b    = wts;                 // 524288
  u16*   w2b    = wts + 524288;        // 262144
  u16*   wmub   = wts + 786432;        // 262144
  u16*   wlvb   = wts + 1048576;       // 262144
  u16*   wd1b   = wts + 1310720;       // 262144
  u16*   wd2b   = wts + 1572864;       // 524288
  u16*   ws_h   = (u16*)(ws + 20971520);       // 8 MB
  u16*   encb   = (u16*)(ws + 29360128);       // 8 MB
  u16*   zb     = (u16*)(ws + 37748736);       // 8 MB
  float* ws_u   = (float*)(ws);                // 32 MB (after phase 1)
  float* pub    = (float*)(ws + 33554432);     // 32 MB (raw state history, s+2)

  dim3 blk(256);
  // casts (f32 -> bf16)
  cast_ker<<<8192, blk, 0, stream>>>(data,   data_b, 2097152);
  cast_ker<<<512,  blk, 0, stream>>>(W_enc1, w1b,    131072);
  cast_ker<<<256,  blk, 0, stream>>>(W_enc2, w2b,    65536);
  cast_ker<<<256,  blk, 0, stream>>>(W_mu,   wmub,   65536);
  cast_ker<<<256,  blk, 0, stream>>>(W_lv,   wlvb,   65536);
  cast_ker<<<256,  blk, 0, stream>>>(W_dec1, wd1b,   65536);
  cast_ker<<<512,  blk, 0, stream>>>(W_dec2, wd2b,   131072);

  // VAE
  gemm_bt<1,1,0,1><<<dim3(64,4), blk, 0, stream>>>(data_b, w1b,  b_enc1, nullptr, ws_h,   8192, 512, 1024);
  gemm_bt<1,1,1,1><<<dim3(64,4), blk, 0, stream>>>(ws_h,   w2b,  b_enc2, out_enc, encb,   8192, 512, 512);
  gemm_bt<0,1,1,0><<<dim3(64,4), blk, 0, stream>>>(encb,   wmub, b_mu,   out_mu,  nullptr,8192, 512, 512);
  gemm_bt<0,1,1,0><<<dim3(64,4), blk, 0, stream>>>(encb,   wlvb, b_lv,   out_lv,  nullptr,8192, 512, 512);
  z_ker<<<4096, blk, 0, stream>>>(out_mu, out_lv, eps, out_z, zb, 1048576);
  gemm_bt<1,1,0,1><<<dim3(64,4), blk, 0, stream>>>(zb,     wd1b, b_dec1, nullptr, ws_h,   8192, 512, 512);
  gemm_bt<0,1,1,0><<<dim3(64,8), blk, 0, stream>>>(ws_h,   wd2b, b_dec2, out_dec, nullptr,8192, 1024, 512);

  // u = z @ Win^T in ~f32 precision (feeds 8192-step recurrence)
  gemm_split<<<dim3(64,8), blk, 0, stream>>>(out_z, Win, ws_u, 8192, 1024, 512);

  // zero pub AFTER phase-1 kernels that alias it (encb/zb) are done, before reservoir.
  // Required every call: pub persists across graph replays and 0 == "not ready".
  (void)hipMemsetAsync(pub, 0, (size_t)33554432, stream);

  // reservoir + readout
  reservoir_ker<<<RG, blk, 0, stream>>>(Wrec, ws_u, pub);
  pred_ker<<<32, blk, 0, stream>>>(pub, W_out, out_pred);
}